// Round 1
// baseline (106.462 us; speedup 1.0000x reference)
//
#include <hip/hip_runtime.h>
#include <stdint.h>

#define NDEC 8192
#define NENC 8192
#define IND  512
#define OUTD 64

typedef __attribute__((ext_vector_type(8))) short bf16x8;
typedef __attribute__((ext_vector_type(4))) float f32x4;

static __device__ __forceinline__ unsigned short f2bf(float f) {
    union { float f; uint32_t u; } v; v.f = f;
    uint32_t u = v.u;
    u += 0x7FFFu + ((u >> 16) & 1u);   // RNE
    return (unsigned short)(u >> 16);
}
static __device__ __forceinline__ uint32_t pack2bf(float a, float b) {
    return (uint32_t)f2bf(a) | ((uint32_t)f2bf(b) << 16);
}
static __device__ __forceinline__ bf16x8 cvt8(float4 a, float4 b) {
    bf16x8 r;
    r[0]=(short)f2bf(a.x); r[1]=(short)f2bf(a.y); r[2]=(short)f2bf(a.z); r[3]=(short)f2bf(a.w);
    r[4]=(short)f2bf(b.x); r[5]=(short)f2bf(b.y); r[6]=(short)f2bf(b.z); r[7]=(short)f2bf(b.w);
    return r;
}

// ---------------------------------------------------------------------------
// Stage 1: projections. mat 0: q = x@Wq -> qbuf[8192][64] bf16 (row-major)
//          mat 1: k = E@Wk -> kbuf[8192][64] bf16 (row-major)
//          mat 2: vT = (E@Wv)^T -> vT[64][8192] bf16
// W staged in LDS transposed (WT[n][k]) bf16, XOR-swizzled: byte ^= (n&7)<<4
// ---------------------------------------------------------------------------
__global__ __launch_bounds__(256) void proj_kernel(
    const float* __restrict__ x, const float* __restrict__ emb,
    const float* __restrict__ wq, const float* __restrict__ wk, const float* __restrict__ wv,
    unsigned short* __restrict__ qbuf, unsigned short* __restrict__ kbuf,
    unsigned short* __restrict__ vT)
{
    __shared__ unsigned short wt[64 * 512];   // 64 KiB
    const int mat = blockIdx.y;
    const float* W = (mat == 0) ? wq : ((mat == 1) ? wk : wv);
    const int t = threadIdx.x;

    // stage W[512][64] f32 -> WT bf16 swizzled
    #pragma unroll 4
    for (int i = 0; i < 128; ++i) {
        int idx = i * 256 + t;
        int k = idx >> 6, n = idx & 63;
        unsigned short b = f2bf(W[idx]);
        uint32_t byteoff = (uint32_t)n * 1024u + (((uint32_t)k * 2u) ^ (((uint32_t)(n & 7)) << 4));
        *(unsigned short*)((char*)wt + byteoff) = b;
    }
    __syncthreads();

    const int wave = t >> 6, lane = t & 63;
    const int lo = lane & 15, g = lane >> 4;

    f32x4 acc[4];
    #pragma unroll
    for (int nf = 0; nf < 4; ++nf) acc[nf] = (f32x4){0.f, 0.f, 0.f, 0.f};

    if (mat < 2) {
        const float* A = (mat == 0) ? x : emb;
        const int rbase = blockIdx.x * 64 + wave * 16;
        const float* arow = A + (size_t)(rbase + lo) * IND;
        #pragma unroll 2
        for (int ks = 0; ks < 16; ++ks) {
            int k0 = ks * 32 + g * 8;
            float4 a0 = *(const float4*)(arow + k0);
            float4 a1 = *(const float4*)(arow + k0 + 4);
            bf16x8 af = cvt8(a0, a1);
            #pragma unroll
            for (int nf = 0; nf < 4; ++nf) {
                int n = nf * 16 + lo;
                uint32_t byteoff = (uint32_t)n * 1024u + (((uint32_t)(k0 * 2)) ^ (((uint32_t)(n & 7)) << 4));
                bf16x8 bfv = *(const bf16x8*)((const char*)wt + byteoff);
                acc[nf] = __builtin_amdgcn_mfma_f32_16x16x32_bf16(af, bfv, acc[nf], 0, 0, 0);
            }
        }
        unsigned short* obuf = (mat == 0) ? qbuf : kbuf;
        #pragma unroll
        for (int nf = 0; nf < 4; ++nf)
            #pragma unroll
            for (int r = 0; r < 4; ++r)
                obuf[(size_t)(rbase + 4 * g + r) * OUTD + nf * 16 + lo] = f2bf(acc[nf][r]);
    } else {
        // vT[f][tok] = sum_k Wv[k][f] * E[tok][k];  A = WT (m=f), B = E^T (n=tok)
        const int f = wave * 16 + lo;
        const int tbase = blockIdx.x * 64;
        #pragma unroll 2
        for (int ks = 0; ks < 16; ++ks) {
            int k0 = ks * 32 + g * 8;
            uint32_t byteoff = (uint32_t)f * 1024u + (((uint32_t)(k0 * 2)) ^ (((uint32_t)(f & 7)) << 4));
            bf16x8 wf = *(const bf16x8*)((const char*)wt + byteoff);
            #pragma unroll
            for (int nf = 0; nf < 4; ++nf) {
                const float* erow = emb + (size_t)(tbase + nf * 16 + lo) * IND + k0;
                float4 e0 = *(const float4*)(erow);
                float4 e1 = *(const float4*)(erow + 4);
                bf16x8 ef = cvt8(e0, e1);
                acc[nf] = __builtin_amdgcn_mfma_f32_16x16x32_bf16(wf, ef, acc[nf], 0, 0, 0);
            }
        }
        #pragma unroll
        for (int nf = 0; nf < 4; ++nf)
            #pragma unroll
            for (int r = 0; r < 4; ++r)
                vT[(size_t)(wave * 16 + 4 * g + r) * NENC + tbase + nf * 16 + lo] = f2bf(acc[nf][r]);
    }
}

// ---------------------------------------------------------------------------
// Stage 2: flash attention, swapped QK^T (S^T = K·Q^T) and swapped PV
// (O^T = V^T·P^T). Each wave: 32 q-rows; block = 4 waves = 128 rows.
// Grid (NDEC/128, nsplit); partial (O, m, l) per split in exp2 domain.
// ---------------------------------------------------------------------------
__global__ __launch_bounds__(256) void attn_kernel(
    const unsigned short* __restrict__ qbuf, const unsigned short* __restrict__ kbuf,
    const unsigned short* __restrict__ vT,
    float* __restrict__ Opart, float* __restrict__ Mpart, float* __restrict__ Lpart,
    int chunk)
{
    const int t = threadIdx.x;
    const int wave = t >> 6, lane = t & 63;
    const int lo = lane & 15, g = lane >> 4;
    const int rowbase = blockIdx.x * 128 + wave * 32;
    const int split = blockIdx.y;
    const int tok0 = split * chunk;
    const float c = 0.125f * 1.44269504088896340736f;  // scale * log2(e)

    // Q B-fragments: q[rf][ks], row = rowbase + rf*16 + lo, feats ks*32+g*8..+7
    bf16x8 qf[2][2];
    #pragma unroll
    for (int rf = 0; rf < 2; ++rf)
        #pragma unroll
        for (int ks = 0; ks < 2; ++ks)
            qf[rf][ks] = *(const bf16x8*)(qbuf + (size_t)(rowbase + rf * 16 + lo) * OUTD + ks * 32 + g * 8);

    f32x4 o[4][2];
    #pragma unroll
    for (int ff = 0; ff < 4; ++ff)
        #pragma unroll
        for (int rf = 0; rf < 2; ++rf) o[ff][rf] = (f32x4){0.f, 0.f, 0.f, 0.f};
    float m_run[2] = {-1e30f, -1e30f};
    float l_part[2] = {0.f, 0.f};

    for (int tk = 0; tk < chunk; tk += 32) {
        const int tb = tok0 + tk;
        // S^T tile: s[rf][tf]; token (within 32) = tf*16 + 4g + r, row = rf*16 + lo
        f32x4 s[2][2];
        #pragma unroll
        for (int rf = 0; rf < 2; ++rf)
            #pragma unroll
            for (int tf = 0; tf < 2; ++tf) s[rf][tf] = (f32x4){0.f, 0.f, 0.f, 0.f};
        #pragma unroll
        for (int tf = 0; tf < 2; ++tf) {
            #pragma unroll
            for (int ks = 0; ks < 2; ++ks) {
                bf16x8 kf = *(const bf16x8*)(kbuf + (size_t)(tb + tf * 16 + lo) * OUTD + ks * 32 + g * 8);
                #pragma unroll
                for (int rf = 0; rf < 2; ++rf)
                    s[rf][tf] = __builtin_amdgcn_mfma_f32_16x16x32_bf16(kf, qf[rf][ks], s[rf][tf], 0, 0, 0);
            }
        }
        // V^T A-fragments: vf[ff], f = ff*16+lo, tokens tb + g*8..+7
        bf16x8 vf[4];
        #pragma unroll
        for (int ff = 0; ff < 4; ++ff)
            vf[ff] = *(const bf16x8*)(vT + (size_t)(ff * 16 + lo) * NENC + tb + g * 8);

        #pragma unroll
        for (int rf = 0; rf < 2; ++rf) {
            float p[8];
            float mx = -1e30f;
            #pragma unroll
            for (int tf = 0; tf < 2; ++tf)
                #pragma unroll
                for (int r = 0; r < 4; ++r) {
                    float v = s[rf][tf][r] * c;
                    p[tf * 4 + r] = v;
                    mx = fmaxf(mx, v);
                }
            mx = fmaxf(mx, __shfl_xor(mx, 16));
            mx = fmaxf(mx, __shfl_xor(mx, 32));
            float mnew = fmaxf(m_run[rf], mx);
            float fct = __builtin_amdgcn_exp2f(m_run[rf] - mnew);
            m_run[rf] = mnew;
            float sum = 0.f;
            #pragma unroll
            for (int i = 0; i < 8; ++i) {
                p[i] = __builtin_amdgcn_exp2f(p[i] - mnew);
                sum += p[i];
            }
            l_part[rf] = l_part[rf] * fct + sum;
            #pragma unroll
            for (int ff = 0; ff < 4; ++ff) o[ff][rf] *= fct;

            // pack P to bf16 and redistribute: dst lane (group g) needs tokens 8g..8g+7
            uint32_t pk0 = pack2bf(p[0], p[1]);   // tf0 tokens 4g+0,1
            uint32_t pk1 = pack2bf(p[2], p[3]);   // tf0 tokens 4g+2,3
            uint32_t pk2 = pack2bf(p[4], p[5]);   // tf1 tokens 16+4g+0,1
            uint32_t pk3 = pack2bf(p[6], p[7]);   // tf1 tokens 16+4g+2,3
            int src0 = lo + 16 * ((2 * g) & 3);
            int src1 = lo + 16 * ((2 * g + 1) & 3);
            uint32_t a0 = (uint32_t)__shfl((int)pk0, src0);
            uint32_t a1 = (uint32_t)__shfl((int)pk1, src0);
            uint32_t a2 = (uint32_t)__shfl((int)pk0, src1);
            uint32_t a3 = (uint32_t)__shfl((int)pk1, src1);
            uint32_t b0 = (uint32_t)__shfl((int)pk2, src0);
            uint32_t b1 = (uint32_t)__shfl((int)pk3, src0);
            uint32_t b2 = (uint32_t)__shfl((int)pk2, src1);
            uint32_t b3 = (uint32_t)__shfl((int)pk3, src1);
            bool hi = (g >= 2);
            union { uint32_t u[4]; bf16x8 v; } pu;
            pu.u[0] = hi ? b0 : a0;
            pu.u[1] = hi ? b1 : a1;
            pu.u[2] = hi ? b2 : a2;
            pu.u[3] = hi ? b3 : a3;
            bf16x8 pf = pu.v;
            #pragma unroll
            for (int ff = 0; ff < 4; ++ff)
                o[ff][rf] = __builtin_amdgcn_mfma_f32_16x16x32_bf16(vf[ff], pf, o[ff][rf], 0, 0, 0);
        }
    }

    // finalize partials
    #pragma unroll
    for (int rf = 0; rf < 2; ++rf) {
        float l = l_part[rf];
        l += __shfl_xor(l, 16);
        l += __shfl_xor(l, 32);
        int row = rowbase + rf * 16 + lo;
        if (g == 0) {
            Mpart[(size_t)split * NDEC + row] = m_run[rf];
            Lpart[(size_t)split * NDEC + row] = l;
        }
        #pragma unroll
        for (int ff = 0; ff < 4; ++ff) {
            float4 st;
            st.x = o[ff][rf][0]; st.y = o[ff][rf][1]; st.z = o[ff][rf][2]; st.w = o[ff][rf][3];
            *(float4*)(Opart + ((size_t)split * NDEC + row) * OUTD + ff * 16 + 4 * g) = st;
        }
    }
}

// ---------------------------------------------------------------------------
// Stage 3: combine splits (exp2 domain) and normalize.
// ---------------------------------------------------------------------------
__global__ __launch_bounds__(256) void combine_kernel(
    const float* __restrict__ Opart, const float* __restrict__ Mpart,
    const float* __restrict__ Lpart, float* __restrict__ out, int nsplit)
{
    int idx = blockIdx.x * 256 + threadIdx.x;   // row*16 + f4
    int row = idx >> 4;
    int f4 = (idx & 15) * 4;
    float M = -1e30f;
    for (int s = 0; s < nsplit; ++s) M = fmaxf(M, Mpart[(size_t)s * NDEC + row]);
    float L = 0.f;
    float ax = 0.f, ay = 0.f, az = 0.f, aw = 0.f;
    for (int s = 0; s < nsplit; ++s) {
        float w = __builtin_amdgcn_exp2f(Mpart[(size_t)s * NDEC + row] - M);
        L += Lpart[(size_t)s * NDEC + row] * w;
        float4 op = *(const float4*)(Opart + ((size_t)s * NDEC + row) * OUTD + f4);
        ax += op.x * w; ay += op.y * w; az += op.z * w; aw += op.w * w;
    }
    float inv = 1.f / L;
    float4 st; st.x = ax * inv; st.y = ay * inv; st.z = az * inv; st.w = aw * inv;
    *(float4*)(out + (size_t)row * OUTD + f4) = st;
}

extern "C" void kernel_launch(void* const* d_in, const int* in_sizes, int n_in,
                              void* d_out, int out_size, void* d_ws, size_t ws_size,
                              hipStream_t stream) {
    const float* x   = (const float*)d_in[0];
    const float* emb = (const float*)d_in[1];
    const float* wq  = (const float*)d_in[2];
    const float* wk  = (const float*)d_in[3];
    const float* wv  = (const float*)d_in[4];
    float* out = (float*)d_out;
    char* ws = (char*)d_ws;

    unsigned short* qbuf = (unsigned short*)ws;                  // 1 MiB
    unsigned short* kbuf = (unsigned short*)(ws + (1u << 20));   // 1 MiB
    unsigned short* vTb  = (unsigned short*)(ws + (2u << 20));   // 1 MiB
    const size_t base = (size_t)3u << 20;
    const size_t per_split = (size_t)NDEC * OUTD * 4 + 2 * (size_t)NDEC * 4; // O + m + l
    int nsplit = 16;
    while (nsplit > 1 && base + (size_t)nsplit * per_split > ws_size) nsplit >>= 1;
    float* Opart = (float*)(ws + base);
    float* Mpart = (float*)(ws + base + (size_t)nsplit * NDEC * OUTD * 4);
    float* Lpart = (float*)(ws + base + (size_t)nsplit * NDEC * OUTD * 4 + (size_t)nsplit * NDEC * 4);

    hipLaunchKernelGGL(proj_kernel, dim3(NDEC / 64, 3), dim3(256), 0, stream,
                       x, emb, wq, wk, wv, qbuf, kbuf, vTb);
    hipLaunchKernelGGL(attn_kernel, dim3(NDEC / 128, nsplit), dim3(256), 0, stream,
                       qbuf, kbuf, vTb, Opart, Mpart, Lpart, NENC / nsplit);
    hipLaunchKernelGGL(combine_kernel, dim3((NDEC * 16) / 256), dim3(256), 0, stream,
                       Opart, Mpart, Lpart, out, nsplit);
}